// Round 2
// baseline (2242.558 us; speedup 1.0000x reference)
//
#include <hip/hip_runtime.h>
#include <math.h>

#define NEG_SLOPE 0.05f

__device__ __forceinline__ float leaky(float x){ return x >= 0.f ? x : NEG_SLOPE * x; }

// ---------------- K0: zero degree arrays ----------------
__global__ __launch_bounds__(256) void k_init(int* deg_n, int* deg_e, int N){
    int t = blockIdx.x * blockDim.x + threadIdx.x;
    int stride = gridDim.x * blockDim.x;
    for (int i = t; i < N; i += stride){ deg_n[i] = 0; deg_e[i] = 0; }
}

// ---------------- K1: h = x @ Wn^T, hi/hj/he per-node scalars ----------------
__global__ __launch_bounds__(256) void k_node(const float* __restrict__ x, const float* __restrict__ Wn,
        const float* __restrict__ a_node, const float* __restrict__ a_edge,
        float* __restrict__ h, float* __restrict__ hi, float* __restrict__ hj, float* __restrict__ he,
        int N){
    __shared__ float Wt[128 * 64];          // Wt[f*64+d] = Wn[d*128+f]
    for (int i = threadIdx.x; i < 128 * 64; i += 256){
        int f = i >> 6, d = i & 63;
        Wt[i] = Wn[d * 128 + f];
    }
    __syncthreads();
    int lane = threadIdx.x & 63;
    int node = (blockIdx.x * 256 + threadIdx.x) >> 6;   // one wave per node
    if (node >= N) return;
    float xv0 = x[(size_t)node * 128 + lane];
    float xv1 = x[(size_t)node * 128 + 64 + lane];
    float acc = 0.f;
    #pragma unroll
    for (int f = 0; f < 64; f++){
        float xf = __shfl(xv0, f);
        acc = fmaf(xf, Wt[f * 64 + lane], acc);
    }
    #pragma unroll
    for (int f = 0; f < 64; f++){
        float xf = __shfl(xv1, f);
        acc = fmaf(xf, Wt[(64 + f) * 64 + lane], acc);
    }
    h[(size_t)node * 64 + lane] = acc;
    float p1 = acc * a_node[lane];
    float p2 = acc * a_node[64 + lane];
    float p3 = acc * a_edge[lane];
    #pragma unroll
    for (int k = 1; k < 64; k <<= 1){
        p1 += __shfl_xor(p1, k);
        p2 += __shfl_xor(p2, k);
        p3 += __shfl_xor(p3, k);
    }
    if (lane == 0){ hi[node] = p1; hj[node] = p2; he[node] = p3; }
}

// ---------------- K2: g = ea @ We^T (wave per edge), ge = g . a_edge[64:], degree counts ----------------
__global__ __launch_bounds__(256) void k_g(const float* __restrict__ ea, const int* __restrict__ idx,
        const float* __restrict__ We, const float* __restrict__ a_edge,
        float* __restrict__ g, float* __restrict__ ge,
        int* __restrict__ deg_n, int* __restrict__ deg_e, int E){
    __shared__ float Wet[64 * 64];   // Wet[f*64+d] = We[d*64+f]
    for (int i = threadIdx.x; i < 64 * 64; i += 256){
        int f = i >> 6, d = i & 63;
        Wet[i] = We[d * 64 + f];
    }
    __syncthreads();
    int lane = threadIdx.x & 63;
    int k = (blockIdx.x * 256 + threadIdx.x) >> 6;
    if (k >= E) return;
    float eav = ea[(size_t)k * 64 + lane];
    float gd = 0.f;
    #pragma unroll
    for (int f = 0; f < 64; f++){
        float eaf = __shfl(eav, f);
        gd = fmaf(eaf, Wet[f * 64 + lane], gd);
    }
    g[(size_t)k * 64 + lane] = gd;
    float pr = gd * a_edge[64 + lane];
    #pragma unroll
    for (int t = 1; t < 64; t <<= 1) pr += __shfl_xor(pr, t);
    if (lane == 0){
        ge[k] = pr;
        int i0 = idx[k], i1 = idx[E + k];
        atomicAdd(&deg_n[i0], 1);
        atomicAdd(&deg_e[i0], 1);
        atomicAdd(&deg_e[i1], 1);
    }
}

// ---------------- K3: exclusive scan (one block per array) ----------------
__global__ __launch_bounds__(1024) void k_scan(const int* __restrict__ deg_n, int* __restrict__ off_n, int* __restrict__ cur_n,
                                               const int* __restrict__ deg_e, int* __restrict__ off_e, int* __restrict__ cur_e,
                                               int N){
    const int* deg = blockIdx.x ? deg_e : deg_n;
    int* off = blockIdx.x ? off_e : off_n;
    int* cur = blockIdx.x ? cur_e : cur_n;
    __shared__ int sdata[1024];
    int running = 0;
    for (int base = 0; base < N; base += 1024){
        int i = base + threadIdx.x;
        int v = (i < N) ? deg[i] : 0;
        sdata[threadIdx.x] = v;
        __syncthreads();
        #pragma unroll
        for (int ofs = 1; ofs < 1024; ofs <<= 1){
            int t = (threadIdx.x >= ofs) ? sdata[threadIdx.x - ofs] : 0;
            __syncthreads();
            sdata[threadIdx.x] += t;
            __syncthreads();
        }
        int excl = sdata[threadIdx.x] - v;
        if (i < N){ off[i] = running + excl; cur[i] = running + excl; }
        int tot = sdata[1023];
        __syncthreads();
        running += tot;
    }
}

// ---------------- K4: fill adjacency (counting-sort scatter, int atomics) ----------------
__global__ __launch_bounds__(256) void k_fill(const int* __restrict__ idx,
        int* __restrict__ cur_n, int* __restrict__ cur_e,
        int* __restrict__ adj_n, int* __restrict__ adj_e, int E){
    int k = blockIdx.x * 256 + threadIdx.x;
    if (k >= E) return;
    int i0 = idx[k], i1 = idx[E + k];
    int pn = atomicAdd(&cur_n[i0], 1);
    adj_n[pn] = i1;                        // store source node directly
    int p0 = atomicAdd(&cur_e[i0], 1);
    adj_e[p0] = k;
    int p1 = atomicAdd(&cur_e[i1], 1);
    adj_e[p1] = k;
}

// ---------------- K5: per-node online-softmax gather, both branches, write out ----------------
__global__ __launch_bounds__(256) void k_out(const float* __restrict__ h,
        const float* __restrict__ hi, const float* __restrict__ hj, const float* __restrict__ he,
        const float* __restrict__ g, const float* __restrict__ ge,
        const int* __restrict__ off_n, const int* __restrict__ deg_n,
        const int* __restrict__ off_e, const int* __restrict__ deg_e,
        const int* __restrict__ adj_n, const int* __restrict__ adj_e,
        float* __restrict__ out, int N){
    int lane = threadIdx.x & 63;
    int i = (blockIdx.x * 256 + threadIdx.x) >> 6;
    if (i >= N) return;
    float hi_i = hi[i], he_i = he[i];

    // ----- node branch (self-loop seeds state) -----
    float m = leaky(hi_i + hj[i]);
    float ssum = 1.f;
    float acc = h[(size_t)i * 64 + lane];
    int s0 = off_n[i], cnt = deg_n[i];
    int p = s0, e = s0 + cnt;
    #define ONL_N(B, V) { float ev = leaky(hi_i + (B)); float mn = fmaxf(m, ev); \
        float fsc = __expf(m - mn); float w = __expf(ev - mn); \
        acc = acc * fsc + w * (V); ssum = ssum * fsc + w; m = mn; }
    for (; p + 4 <= e; p += 4){
        int j0 = adj_n[p], j1 = adj_n[p+1], j2 = adj_n[p+2], j3 = adj_n[p+3];
        float b0 = hj[j0], b1 = hj[j1], b2 = hj[j2], b3 = hj[j3];
        float v0 = h[(size_t)j0 * 64 + lane];
        float v1 = h[(size_t)j1 * 64 + lane];
        float v2 = h[(size_t)j2 * 64 + lane];
        float v3 = h[(size_t)j3 * 64 + lane];
        ONL_N(b0, v0); ONL_N(b1, v1); ONL_N(b2, v2); ONL_N(b3, v3);
    }
    for (; p < e; p++){
        int j = adj_n[p];
        float b = hj[j];
        float v = h[(size_t)j * 64 + lane];
        ONL_N(b, v);
    }
    float vn = acc / ssum / (float)(cnt + 1);

    // ----- edge branch -----
    float m2 = -1e30f, ssum2 = 0.f, acc2 = 0.f;
    int s1 = off_e[i], cnt2 = deg_e[i];
    p = s1; e = s1 + cnt2;
    #define ONL_E(B, V) { float ev = leaky(he_i + (B)); float mn = fmaxf(m2, ev); \
        float fsc = __expf(m2 - mn); float w = __expf(ev - mn); \
        acc2 = acc2 * fsc + w * (V); ssum2 = ssum2 * fsc + w; m2 = mn; }
    for (; p + 4 <= e; p += 4){
        int k0 = adj_e[p], k1 = adj_e[p+1], k2 = adj_e[p+2], k3 = adj_e[p+3];
        float b0 = ge[k0], b1 = ge[k1], b2 = ge[k2], b3 = ge[k3];
        float v0 = g[(size_t)k0 * 64 + lane];
        float v1 = g[(size_t)k1 * 64 + lane];
        float v2 = g[(size_t)k2 * 64 + lane];
        float v3 = g[(size_t)k3 * 64 + lane];
        ONL_E(b0, v0); ONL_E(b1, v1); ONL_E(b2, v2); ONL_E(b3, v3);
    }
    for (; p < e; p++){
        int k = adj_e[p];
        float b = ge[k];
        float v = g[(size_t)k * 64 + lane];
        ONL_E(b, v);
    }
    float ve = (cnt2 > 0) ? (acc2 / ssum2 / (float)cnt2) : 0.f;

    out[(size_t)i * 128 + lane] = leaky(vn);
    out[(size_t)i * 128 + 64 + lane] = leaky(ve);
}

extern "C" void kernel_launch(void* const* d_in, const int* in_sizes, int n_in,
                              void* d_out, int out_size, void* d_ws, size_t ws_size,
                              hipStream_t stream){
    const float* x      = (const float*)d_in[0];
    const float* ea     = (const float*)d_in[1];
    const int*   idx    = (const int*)  d_in[2];
    const float* Wn     = (const float*)d_in[3];
    const float* We     = (const float*)d_in[4];
    const float* a_node = (const float*)d_in[5];
    const float* a_edge = (const float*)d_in[6];
    float* out = (float*)d_out;

    const int N = in_sizes[0] / 128;   // 50000
    const int E = in_sizes[1] / 64;    // 800000

    float* p = (float*)d_ws;
    float* h   = p; p += (size_t)N * 64;
    float* hi  = p; p += N;
    float* hj  = p; p += N;
    float* he  = p; p += N;
    float* g   = p; p += (size_t)E * 64;
    float* ge  = p; p += E;
    int* deg_n = (int*)p; p += N;
    int* deg_e = (int*)p; p += N;
    int* off_n = (int*)p; p += N;
    int* off_e = (int*)p; p += N;
    int* cur_n = (int*)p; p += N;
    int* cur_e = (int*)p; p += N;
    int* adj_n = (int*)p; p += E;
    int* adj_e = (int*)p; p += (size_t)2 * E;

    k_init<<<256, 256, 0, stream>>>(deg_n, deg_e, N);
    k_node<<<(N + 3) / 4, 256, 0, stream>>>(x, Wn, a_node, a_edge, h, hi, hj, he, N);
    k_g<<<(E + 3) / 4, 256, 0, stream>>>(ea, idx, We, a_edge, g, ge, deg_n, deg_e, E);
    k_scan<<<2, 1024, 0, stream>>>(deg_n, off_n, cur_n, deg_e, off_e, cur_e, N);
    k_fill<<<(E + 255) / 256, 256, 0, stream>>>(idx, cur_n, cur_e, adj_n, adj_e, E);
    k_out<<<(N + 3) / 4, 256, 0, stream>>>(h, hi, hj, he, g, ge, off_n, deg_n, off_e, deg_e, adj_n, adj_e, out, N);
}

// Round 3
// 798.816 us; speedup vs baseline: 2.8074x; 2.8074x over previous
//
#include <hip/hip_runtime.h>
#include <math.h>

#define NEG_SLOPE 0.05f

__device__ __forceinline__ float leaky(float x){ return x >= 0.f ? x : NEG_SLOPE * x; }

// ---------------- K0: zero degree arrays ----------------
__global__ __launch_bounds__(256) void k_init(int* deg_n, int* deg_e, int N){
    int t = blockIdx.x * blockDim.x + threadIdx.x;
    int stride = gridDim.x * blockDim.x;
    for (int i = t; i < N; i += stride){ deg_n[i] = 0; deg_e[i] = 0; }
}

// ---------------- tiled GEMM: C[M x 64] = A[M x K] @ B[64 x K]^T ----------------
// block = 256 threads, tile 64 rows x 64 cols, each thread computes 4x4.
template<int K, bool LEAKY>
__global__ __launch_bounds__(256) void k_gemm64(const float* __restrict__ A, const float* __restrict__ B,
                                                float* __restrict__ C, int M, int ldC){
    __shared__ float As[K][68];   // +4 pad keeps 16B alignment, breaks bank conflicts
    __shared__ float Bs[K][68];
    const int m0 = blockIdx.x * 64;
    const int t = threadIdx.x;

    // load B[64 x K] -> Bs[k][d]. i: d = i%64, kq = i/64 (consecutive lanes -> consecutive d)
    for (int i = t; i < 16 * K; i += 256){
        int d = i & 63, kq = i >> 6;
        float4 b = *(const float4*)&B[(size_t)d * K + kq * 4];
        Bs[kq*4+0][d] = b.x; Bs[kq*4+1][d] = b.y; Bs[kq*4+2][d] = b.z; Bs[kq*4+3][d] = b.w;
    }
    // load A rows m0..m0+63 -> As[k][r]
    for (int i = t; i < 16 * K; i += 256){
        int r = i & 63, kq = i >> 6;
        int m = m0 + r;
        float4 a = make_float4(0.f, 0.f, 0.f, 0.f);
        if (m < M) a = *(const float4*)&A[(size_t)m * K + kq * 4];
        As[kq*4+0][r] = a.x; As[kq*4+1][r] = a.y; As[kq*4+2][r] = a.z; As[kq*4+3][r] = a.w;
    }
    __syncthreads();

    const int tx = t & 15, ty = t >> 4;    // 16 x 16 thread grid
    float acc[4][4] = {};
    #pragma unroll 4
    for (int k = 0; k < K; k++){
        float4 a4 = *(const float4*)&As[k][ty * 4];
        float4 b4 = *(const float4*)&Bs[k][tx * 4];
        float av[4] = {a4.x, a4.y, a4.z, a4.w};
        float bv[4] = {b4.x, b4.y, b4.z, b4.w};
        #pragma unroll
        for (int r = 0; r < 4; r++)
            #pragma unroll
            for (int c = 0; c < 4; c++)
                acc[r][c] = fmaf(av[r], bv[c], acc[r][c]);
    }
    #pragma unroll
    for (int r = 0; r < 4; r++){
        int m = m0 + ty * 4 + r;
        if (m < M){
            float4 o;
            o.x = LEAKY ? leaky(acc[r][0]) : acc[r][0];
            o.y = LEAKY ? leaky(acc[r][1]) : acc[r][1];
            o.z = LEAKY ? leaky(acc[r][2]) : acc[r][2];
            o.w = LEAKY ? leaky(acc[r][3]) : acc[r][3];
            *(float4*)&C[(size_t)m * ldC + tx * 4] = o;
        }
    }
}

// ---------------- K2: per-node scalars hi/hj/he from h ----------------
__global__ __launch_bounds__(256) void k_scal(const float* __restrict__ h,
        const float* __restrict__ a_node, const float* __restrict__ a_edge,
        float* __restrict__ hi, float* __restrict__ hj, float* __restrict__ he, int N){
    int i = blockIdx.x * 256 + threadIdx.x;
    if (i >= N) return;
    const float4* hr = (const float4*)(h + (size_t)i * 64);
    const float4* a1 = (const float4*)a_node;
    const float4* a2 = (const float4*)(a_node + 64);
    const float4* a3 = (const float4*)a_edge;
    float s1 = 0.f, s2 = 0.f, s3 = 0.f;
    #pragma unroll
    for (int q = 0; q < 16; q++){
        float4 v = hr[q], w1 = a1[q], w2 = a2[q], w3 = a3[q];
        s1 += v.x*w1.x + v.y*w1.y + v.z*w1.z + v.w*w1.w;
        s2 += v.x*w2.x + v.y*w2.y + v.z*w2.z + v.w*w2.w;
        s3 += v.x*w3.x + v.y*w3.y + v.z*w3.z + v.w*w3.w;
    }
    hi[i] = s1; hj[i] = s2; he[i] = s3;
}

// ---------------- K3: ge[k] = ea[k] . (We^T a_edge[64:]), degree counts ----------------
__global__ __launch_bounds__(256) void k_ge(const float* __restrict__ ea, const int* __restrict__ idx,
        const float* __restrict__ We, const float* __restrict__ a_edge,
        float* __restrict__ ge, int* __restrict__ deg_n, int* __restrict__ deg_e, int E){
    __shared__ float v[64];
    if (threadIdx.x < 64){
        float s = 0.f;
        for (int d = 0; d < 64; d++) s = fmaf(We[d * 64 + threadIdx.x], a_edge[64 + d], s);
        v[threadIdx.x] = s;
    }
    __syncthreads();
    int k = blockIdx.x * 256 + threadIdx.x;
    if (k >= E) return;
    const float4* row = (const float4*)(ea + (size_t)k * 64);
    float s = 0.f;
    #pragma unroll
    for (int q = 0; q < 16; q++){
        float4 r = row[q];
        s = fmaf(r.x, v[4*q+0], s);
        s = fmaf(r.y, v[4*q+1], s);
        s = fmaf(r.z, v[4*q+2], s);
        s = fmaf(r.w, v[4*q+3], s);
    }
    ge[k] = s;
    int i0 = idx[k], i1 = idx[E + k];
    atomicAdd(&deg_n[i0], 1);
    atomicAdd(&deg_e[i0], 1);
    atomicAdd(&deg_e[i1], 1);
}

// ---------------- K4: exclusive scan (one block per array) ----------------
__global__ __launch_bounds__(1024) void k_scan(const int* __restrict__ deg_n, int* __restrict__ off_n, int* __restrict__ cur_n,
                                               const int* __restrict__ deg_e, int* __restrict__ off_e, int* __restrict__ cur_e,
                                               int N){
    const int* deg = blockIdx.x ? deg_e : deg_n;
    int* off = blockIdx.x ? off_e : off_n;
    int* cur = blockIdx.x ? cur_e : cur_n;
    __shared__ int sdata[1024];
    int running = 0;
    for (int base = 0; base < N; base += 1024){
        int i = base + threadIdx.x;
        int vv = (i < N) ? deg[i] : 0;
        sdata[threadIdx.x] = vv;
        __syncthreads();
        #pragma unroll
        for (int ofs = 1; ofs < 1024; ofs <<= 1){
            int t = (threadIdx.x >= ofs) ? sdata[threadIdx.x - ofs] : 0;
            __syncthreads();
            sdata[threadIdx.x] += t;
            __syncthreads();
        }
        int excl = sdata[threadIdx.x] - vv;
        if (i < N){ off[i] = running + excl; cur[i] = running + excl; }
        int tot = sdata[1023];
        __syncthreads();
        running += tot;
    }
}

// ---------------- K5: fill adjacency ----------------
__global__ __launch_bounds__(256) void k_fill(const int* __restrict__ idx,
        int* __restrict__ cur_n, int* __restrict__ cur_e,
        int* __restrict__ adj_n, int* __restrict__ adj_e, int E){
    int k = blockIdx.x * 256 + threadIdx.x;
    if (k >= E) return;
    int i0 = idx[k], i1 = idx[E + k];
    int pn = atomicAdd(&cur_n[i0], 1);
    adj_n[pn] = i1;
    int p0 = atomicAdd(&cur_e[i0], 1);
    adj_e[p0] = k;
    int p1 = atomicAdd(&cur_e[i1], 1);
    adj_e[p1] = k;
}

// online-softmax state update (b, v lane-local; b is wave-uniform in practice)
#define UPD(m, s, a, base, b, v) { float ev = leaky((base) + (b)); float mn = fmaxf(m, ev); \
    float c = __expf(m - mn); float w = __expf(ev - mn); \
    a = a * c + w * (v); s = s * c + w; m = mn; }

// ---------------- K6: per-node gather; node branch -> out[:, :64]; edge branch -> acc_ea ----------------
__global__ __launch_bounds__(256) void k_out(const float* __restrict__ h,
        const float* __restrict__ hi, const float* __restrict__ hj, const float* __restrict__ he,
        const float* __restrict__ ea, const float* __restrict__ ge,
        const int* __restrict__ off_n, const int* __restrict__ deg_n,
        const int* __restrict__ off_e, const int* __restrict__ deg_e,
        const int* __restrict__ adj_n, const int* __restrict__ adj_e,
        float* __restrict__ out, float* __restrict__ acc_ea, int N){
    int lane = threadIdx.x & 63;
    int i = (blockIdx.x * 256 + threadIdx.x) >> 6;
    if (i >= N) return;
    float hi_i = hi[i], he_i = he[i];

    // ----- node branch: 4 independent online states, state0 seeded with self-loop -----
    float m0 = leaky(hi_i + hj[i]), m1 = -1e30f, m2 = -1e30f, m3 = -1e30f;
    float s0 = 1.f, s1 = 0.f, s2 = 0.f, s3 = 0.f;
    float a0 = h[(size_t)i * 64 + lane], a1 = 0.f, a2 = 0.f, a3 = 0.f;
    int cnt = deg_n[i];
    int p = off_n[i], e = p + cnt;
    for (; p + 4 <= e; p += 4){
        int j0 = adj_n[p], j1 = adj_n[p+1], j2 = adj_n[p+2], j3 = adj_n[p+3];
        float b0 = hj[j0], b1 = hj[j1], b2 = hj[j2], b3 = hj[j3];
        float v0 = h[(size_t)j0 * 64 + lane];
        float v1 = h[(size_t)j1 * 64 + lane];
        float v2 = h[(size_t)j2 * 64 + lane];
        float v3 = h[(size_t)j3 * 64 + lane];
        UPD(m0, s0, a0, hi_i, b0, v0);
        UPD(m1, s1, a1, hi_i, b1, v1);
        UPD(m2, s2, a2, hi_i, b2, v2);
        UPD(m3, s3, a3, hi_i, b3, v3);
    }
    for (; p < e; p++){
        int j = adj_n[p];
        float b = hj[j];
        float v = h[(size_t)j * 64 + lane];
        UPD(m0, s0, a0, hi_i, b, v);
    }
    {
        float M = fmaxf(fmaxf(m0, m1), fmaxf(m2, m3));
        float e0 = __expf(m0 - M), e1 = __expf(m1 - M), e2 = __expf(m2 - M), e3 = __expf(m3 - M);
        float S = s0*e0 + s1*e1 + s2*e2 + s3*e3;
        float A = a0*e0 + a1*e1 + a2*e2 + a3*e3;
        out[(size_t)i * 128 + lane] = leaky(A / S / (float)(cnt + 1));
    }

    // ----- edge branch: accumulate raw ea rows (g applied later via GEMM) -----
    m0 = -1e30f; m1 = -1e30f; m2 = -1e30f; m3 = -1e30f;
    s0 = 0.f; s1 = 0.f; s2 = 0.f; s3 = 0.f;
    a0 = 0.f; a1 = 0.f; a2 = 0.f; a3 = 0.f;
    int cnt2 = deg_e[i];
    p = off_e[i]; e = p + cnt2;
    for (; p + 4 <= e; p += 4){
        int k0 = adj_e[p], k1 = adj_e[p+1], k2 = adj_e[p+2], k3 = adj_e[p+3];
        float b0 = ge[k0], b1 = ge[k1], b2 = ge[k2], b3 = ge[k3];
        float v0 = ea[(size_t)k0 * 64 + lane];
        float v1 = ea[(size_t)k1 * 64 + lane];
        float v2 = ea[(size_t)k2 * 64 + lane];
        float v3 = ea[(size_t)k3 * 64 + lane];
        UPD(m0, s0, a0, he_i, b0, v0);
        UPD(m1, s1, a1, he_i, b1, v1);
        UPD(m2, s2, a2, he_i, b2, v2);
        UPD(m3, s3, a3, he_i, b3, v3);
    }
    for (; p < e; p++){
        int k = adj_e[p];
        float b = ge[k];
        float v = ea[(size_t)k * 64 + lane];
        UPD(m0, s0, a0, he_i, b, v);
    }
    {
        float val = 0.f;
        if (cnt2 > 0){
            float M = fmaxf(fmaxf(m0, m1), fmaxf(m2, m3));
            float e0 = __expf(m0 - M), e1 = __expf(m1 - M), e2 = __expf(m2 - M), e3 = __expf(m3 - M);
            float S = s0*e0 + s1*e1 + s2*e2 + s3*e3;
            float A = a0*e0 + a1*e1 + a2*e2 + a3*e3;
            val = A / S / (float)cnt2;
        }
        acc_ea[(size_t)i * 64 + lane] = val;
    }
}

extern "C" void kernel_launch(void* const* d_in, const int* in_sizes, int n_in,
                              void* d_out, int out_size, void* d_ws, size_t ws_size,
                              hipStream_t stream){
    const float* x      = (const float*)d_in[0];
    const float* ea     = (const float*)d_in[1];
    const int*   idx    = (const int*)  d_in[2];
    const float* Wn     = (const float*)d_in[3];
    const float* We     = (const float*)d_in[4];
    const float* a_node = (const float*)d_in[5];
    const float* a_edge = (const float*)d_in[6];
    float* out = (float*)d_out;

    const int N = in_sizes[0] / 128;   // 50000
    const int E = in_sizes[1] / 64;    // 800000

    float* p = (float*)d_ws;
    float* h      = p; p += (size_t)N * 64;
    float* hi     = p; p += N;
    float* hj     = p; p += N;
    float* he     = p; p += N;
    float* ge     = p; p += E;
    float* acc_ea = p; p += (size_t)N * 64;
    int* deg_n = (int*)p; p += N;
    int* deg_e = (int*)p; p += N;
    int* off_n = (int*)p; p += N;
    int* off_e = (int*)p; p += N;
    int* cur_n = (int*)p; p += N;
    int* cur_e = (int*)p; p += N;
    int* adj_n = (int*)p; p += E;
    int* adj_e = (int*)p; p += (size_t)2 * E;

    k_init<<<256, 256, 0, stream>>>(deg_n, deg_e, N);
    k_gemm64<128, false><<<(N + 63) / 64, 256, 0, stream>>>(x, Wn, h, N, 64);
    k_scal<<<(N + 255) / 256, 256, 0, stream>>>(h, a_node, a_edge, hi, hj, he, N);
    k_ge<<<(E + 255) / 256, 256, 0, stream>>>(ea, idx, We, a_edge, ge, deg_n, deg_e, E);
    k_scan<<<2, 1024, 0, stream>>>(deg_n, off_n, cur_n, deg_e, off_e, cur_e, N);
    k_fill<<<(E + 255) / 256, 256, 0, stream>>>(idx, cur_n, cur_e, adj_n, adj_e, E);
    k_out<<<(N + 3) / 4, 256, 0, stream>>>(h, hi, hj, he, ea, ge, off_n, deg_n, off_e, deg_e,
                                           adj_n, adj_e, out, acc_ea, N);
    k_gemm64<64, true><<<(N + 63) / 64, 256, 0, stream>>>(acc_ea, We, out + 64, N, 128);
}

// Round 4
// 794.689 us; speedup vs baseline: 2.8219x; 1.0052x over previous
//
#include <hip/hip_runtime.h>
#include <math.h>

#define NEG_SLOPE 0.05f

__device__ __forceinline__ float leaky(float x){ return x >= 0.f ? x : NEG_SLOPE * x; }

// ---------------- K0: zero degree arrays ----------------
__global__ __launch_bounds__(256) void k_init(int* deg_n, int* deg_e, int N){
    int t = blockIdx.x * blockDim.x + threadIdx.x;
    int stride = gridDim.x * blockDim.x;
    for (int i = t; i < N; i += stride){ deg_n[i] = 0; deg_e[i] = 0; }
}

// ---------------- tiled GEMM: C[M x 64] = A[M x K] @ B[64 x K]^T ----------------
template<int K, bool LEAKY>
__global__ __launch_bounds__(256) void k_gemm64(const float* __restrict__ A, const float* __restrict__ B,
                                                float* __restrict__ C, int M, int ldC){
    __shared__ float As[K][68];
    __shared__ float Bs[K][68];
    const int m0 = blockIdx.x * 64;
    const int t = threadIdx.x;
    for (int i = t; i < 16 * K; i += 256){
        int d = i & 63, kq = i >> 6;
        float4 b = *(const float4*)&B[(size_t)d * K + kq * 4];
        Bs[kq*4+0][d] = b.x; Bs[kq*4+1][d] = b.y; Bs[kq*4+2][d] = b.z; Bs[kq*4+3][d] = b.w;
    }
    for (int i = t; i < 16 * K; i += 256){
        int r = i & 63, kq = i >> 6;
        int m = m0 + r;
        float4 a = make_float4(0.f, 0.f, 0.f, 0.f);
        if (m < M) a = *(const float4*)&A[(size_t)m * K + kq * 4];
        As[kq*4+0][r] = a.x; As[kq*4+1][r] = a.y; As[kq*4+2][r] = a.z; As[kq*4+3][r] = a.w;
    }
    __syncthreads();
    const int tx = t & 15, ty = t >> 4;
    float acc[4][4] = {};
    #pragma unroll 4
    for (int k = 0; k < K; k++){
        float4 a4 = *(const float4*)&As[k][ty * 4];
        float4 b4 = *(const float4*)&Bs[k][tx * 4];
        float av[4] = {a4.x, a4.y, a4.z, a4.w};
        float bv[4] = {b4.x, b4.y, b4.z, b4.w};
        #pragma unroll
        for (int r = 0; r < 4; r++)
            #pragma unroll
            for (int c = 0; c < 4; c++)
                acc[r][c] = fmaf(av[r], bv[c], acc[r][c]);
    }
    #pragma unroll
    for (int r = 0; r < 4; r++){
        int m = m0 + ty * 4 + r;
        if (m < M){
            float4 o;
            o.x = LEAKY ? leaky(acc[r][0]) : acc[r][0];
            o.y = LEAKY ? leaky(acc[r][1]) : acc[r][1];
            o.z = LEAKY ? leaky(acc[r][2]) : acc[r][2];
            o.w = LEAKY ? leaky(acc[r][3]) : acc[r][3];
            *(float4*)&C[(size_t)m * ldC + tx * 4] = o;
        }
    }
}

// ---------------- per-node scalars hi/hj/he ----------------
__global__ __launch_bounds__(256) void k_scal(const float* __restrict__ h,
        const float* __restrict__ a_node, const float* __restrict__ a_edge,
        float* __restrict__ hi, float* __restrict__ hj, float* __restrict__ he, int N){
    int i = blockIdx.x * 256 + threadIdx.x;
    if (i >= N) return;
    const float4* hr = (const float4*)(h + (size_t)i * 64);
    const float4* a1 = (const float4*)a_node;
    const float4* a2 = (const float4*)(a_node + 64);
    const float4* a3 = (const float4*)a_edge;
    float s1 = 0.f, s2 = 0.f, s3 = 0.f;
    #pragma unroll
    for (int q = 0; q < 16; q++){
        float4 v = hr[q], w1 = a1[q], w2 = a2[q], w3 = a3[q];
        s1 += v.x*w1.x + v.y*w1.y + v.z*w1.z + v.w*w1.w;
        s2 += v.x*w2.x + v.y*w2.y + v.z*w2.z + v.w*w2.w;
        s3 += v.x*w3.x + v.y*w3.y + v.z*w3.z + v.w*w3.w;
    }
    hi[i] = s1; hj[i] = s2; he[i] = s3;
}

// ---------------- ge[k] = ea[k] . (We^T a_edge[64:]) (pure stream, no atomics) ----------------
__global__ __launch_bounds__(256) void k_ge(const float* __restrict__ ea,
        const float* __restrict__ We, const float* __restrict__ a_edge,
        float* __restrict__ ge, int E){
    __shared__ float v[64];
    if (threadIdx.x < 64){
        float s = 0.f;
        for (int d = 0; d < 64; d++) s = fmaf(We[d * 64 + threadIdx.x], a_edge[64 + d], s);
        v[threadIdx.x] = s;
    }
    __syncthreads();
    int k = blockIdx.x * 256 + threadIdx.x;
    if (k >= E) return;
    const float4* row = (const float4*)(ea + (size_t)k * 64);
    float s = 0.f;
    #pragma unroll
    for (int q = 0; q < 16; q++){
        float4 r = row[q];
        s = fmaf(r.x, v[4*q+0], s);
        s = fmaf(r.y, v[4*q+1], s);
        s = fmaf(r.z, v[4*q+2], s);
        s = fmaf(r.w, v[4*q+3], s);
    }
    ge[k] = s;
}

// ---------------- XCD-partitioned degree count ----------------
// group g = blockIdx & 7 handles targets in [g*N/8, (g+1)*N/8): atomics stay in one XCD's L2.
__global__ __launch_bounds__(256) void k_count(const int* __restrict__ idx,
        int* __restrict__ deg_n, int* __restrict__ deg_e, int E, int N){
    int g = blockIdx.x & 7;
    int lo = (int)(((long long)g * N) >> 3), hi = (int)(((long long)(g + 1) * N) >> 3);
    int nblk = gridDim.x >> 3;
    int start = ((blockIdx.x >> 3) * 256) + threadIdx.x;
    int stride = nblk * 256;
    for (int k = start; k < E; k += stride){
        int i0 = idx[k], i1 = idx[E + k];
        if (i0 >= lo && i0 < hi){
            atomicAdd(&deg_n[i0], 1);
            atomicAdd(&deg_e[i0], 1);
        }
        if (i1 >= lo && i1 < hi) atomicAdd(&deg_e[i1], 1);
    }
}

// ---------------- chunked shfl scan: 2 blocks, one array each ----------------
__global__ __launch_bounds__(1024) void k_scan(const int* __restrict__ deg_n, int* __restrict__ off_n, int* __restrict__ cur_n,
                                               const int* __restrict__ deg_e, int* __restrict__ off_e, int* __restrict__ cur_e,
                                               int N){
    const int* deg = blockIdx.x ? deg_e : deg_n;
    int* off = blockIdx.x ? off_e : off_n;
    int* cur = blockIdx.x ? cur_e : cur_n;
    const int t = threadIdx.x;
    const int C = (N + 1023) / 1024;
    int base = t * C;
    int lim = min(C, N - base); if (lim < 0) lim = 0;
    int s = 0;
    for (int j = 0; j < lim; j++) s += deg[base + j];
    // block-wide inclusive scan of s
    int lane = t & 63, w = t >> 6;
    int v = s;
    #pragma unroll
    for (int d = 1; d < 64; d <<= 1){ int o = __shfl_up(v, d); if (lane >= d) v += o; }
    __shared__ int wt[16];
    if (lane == 63) wt[w] = v;
    __syncthreads();
    if (w == 0 && lane < 16){
        int z = wt[lane];
        #pragma unroll
        for (int d = 1; d < 16; d <<= 1){ int o = __shfl_up(z, d); if (lane >= d) z += o; }
        wt[lane] = z;
    }
    __syncthreads();
    int run = (w ? wt[w - 1] : 0) + v - s;   // exclusive prefix of this thread's chunk
    for (int j = 0; j < lim; j++){
        off[base + j] = run; cur[base + j] = run;
        run += deg[base + j];
    }
}

// ---------------- XCD-partitioned adjacency fill ----------------
__global__ __launch_bounds__(256) void k_fill(const int* __restrict__ idx,
        int* __restrict__ cur_n, int* __restrict__ cur_e,
        int* __restrict__ adj_n, int* __restrict__ adj_e, int E, int N){
    int g = blockIdx.x & 7;
    int lo = (int)(((long long)g * N) >> 3), hi = (int)(((long long)(g + 1) * N) >> 3);
    int nblk = gridDim.x >> 3;
    int start = ((blockIdx.x >> 3) * 256) + threadIdx.x;
    int stride = nblk * 256;
    for (int k = start; k < E; k += stride){
        int i0 = idx[k], i1 = idx[E + k];
        if (i0 >= lo && i0 < hi){
            adj_n[atomicAdd(&cur_n[i0], 1)] = i1;
            adj_e[atomicAdd(&cur_e[i0], 1)] = k;
        }
        if (i1 >= lo && i1 < hi)
            adj_e[atomicAdd(&cur_e[i1], 1)] = k;
    }
}

// online-softmax state update
#define UPD(m, s, a, base, b, v) { float ev = leaky((base) + (b)); float mn = fmaxf(m, ev); \
    float c = __expf(m - mn); float w = __expf(ev - mn); \
    a = a * c + w * (v); s = s * c + w; m = mn; }

// ---------------- node branch: out[:, :64] ----------------
__global__ __launch_bounds__(256) void k_out_n(const float* __restrict__ h,
        const float* __restrict__ hi, const float* __restrict__ hj,
        const int* __restrict__ off_n, const int* __restrict__ deg_n,
        const int* __restrict__ adj_n,
        float* __restrict__ out, int N){
    int lane = threadIdx.x & 63;
    int i = (blockIdx.x * 256 + threadIdx.x) >> 6;
    if (i >= N) return;
    float hi_i = hi[i];
    float m0 = leaky(hi_i + hj[i]), m1 = -1e30f, m2 = -1e30f, m3 = -1e30f;
    float s0 = 1.f, s1 = 0.f, s2 = 0.f, s3 = 0.f;
    float a0 = h[(size_t)i * 64 + lane], a1 = 0.f, a2 = 0.f, a3 = 0.f;
    int cnt = deg_n[i];
    int p = off_n[i], e = p + cnt;
    for (; p + 4 <= e; p += 4){
        int j0 = adj_n[p], j1 = adj_n[p+1], j2 = adj_n[p+2], j3 = adj_n[p+3];
        float b0 = hj[j0], b1 = hj[j1], b2 = hj[j2], b3 = hj[j3];
        float v0 = h[(size_t)j0 * 64 + lane];
        float v1 = h[(size_t)j1 * 64 + lane];
        float v2 = h[(size_t)j2 * 64 + lane];
        float v3 = h[(size_t)j3 * 64 + lane];
        UPD(m0, s0, a0, hi_i, b0, v0);
        UPD(m1, s1, a1, hi_i, b1, v1);
        UPD(m2, s2, a2, hi_i, b2, v2);
        UPD(m3, s3, a3, hi_i, b3, v3);
    }
    for (; p < e; p++){
        int j = adj_n[p];
        float b = hj[j];
        float v = h[(size_t)j * 64 + lane];
        UPD(m0, s0, a0, hi_i, b, v);
    }
    float M = fmaxf(fmaxf(m0, m1), fmaxf(m2, m3));
    float e0 = __expf(m0 - M), e1 = __expf(m1 - M), e2 = __expf(m2 - M), e3 = __expf(m3 - M);
    float S = s0*e0 + s1*e1 + s2*e2 + s3*e3;
    float A = a0*e0 + a1*e1 + a2*e2 + a3*e3;
    out[(size_t)i * 128 + lane] = leaky(A / S / (float)(cnt + 1));
}

// ---------------- edge branch: acc_ea (raw ea accumulation; We applied by GEMM after) ----------------
__global__ __launch_bounds__(256) void k_out_e(const float* __restrict__ ea,
        const float* __restrict__ he, const float* __restrict__ ge,
        const int* __restrict__ off_e, const int* __restrict__ deg_e,
        const int* __restrict__ adj_e,
        float* __restrict__ acc_ea, int N){
    int lane = threadIdx.x & 63;
    int i = (blockIdx.x * 256 + threadIdx.x) >> 6;
    if (i >= N) return;
    float he_i = he[i];
    float m0 = -1e30f, m1 = -1e30f, m2 = -1e30f, m3 = -1e30f;
    float s0 = 0.f, s1 = 0.f, s2 = 0.f, s3 = 0.f;
    float a0 = 0.f, a1 = 0.f, a2 = 0.f, a3 = 0.f;
    int cnt = deg_e[i];
    int p = off_e[i], e = p + cnt;
    for (; p + 4 <= e; p += 4){
        int k0 = adj_e[p], k1 = adj_e[p+1], k2 = adj_e[p+2], k3 = adj_e[p+3];
        float b0 = ge[k0], b1 = ge[k1], b2 = ge[k2], b3 = ge[k3];
        float v0 = ea[(size_t)k0 * 64 + lane];
        float v1 = ea[(size_t)k1 * 64 + lane];
        float v2 = ea[(size_t)k2 * 64 + lane];
        float v3 = ea[(size_t)k3 * 64 + lane];
        UPD(m0, s0, a0, he_i, b0, v0);
        UPD(m1, s1, a1, he_i, b1, v1);
        UPD(m2, s2, a2, he_i, b2, v2);
        UPD(m3, s3, a3, he_i, b3, v3);
    }
    for (; p < e; p++){
        int k = adj_e[p];
        float b = ge[k];
        float v = ea[(size_t)k * 64 + lane];
        UPD(m0, s0, a0, he_i, b, v);
    }
    float val = 0.f;
    if (cnt > 0){
        float M = fmaxf(fmaxf(m0, m1), fmaxf(m2, m3));
        float e0 = __expf(m0 - M), e1 = __expf(m1 - M), e2 = __expf(m2 - M), e3 = __expf(m3 - M);
        float S = s0*e0 + s1*e1 + s2*e2 + s3*e3;
        float A = a0*e0 + a1*e1 + a2*e2 + a3*e3;
        val = A / S / (float)cnt;
    }
    acc_ea[(size_t)i * 64 + lane] = val;
}

extern "C" void kernel_launch(void* const* d_in, const int* in_sizes, int n_in,
                              void* d_out, int out_size, void* d_ws, size_t ws_size,
                              hipStream_t stream){
    const float* x      = (const float*)d_in[0];
    const float* ea     = (const float*)d_in[1];
    const int*   idx    = (const int*)  d_in[2];
    const float* Wn     = (const float*)d_in[3];
    const float* We     = (const float*)d_in[4];
    const float* a_node = (const float*)d_in[5];
    const float* a_edge = (const float*)d_in[6];
    float* out = (float*)d_out;

    const int N = in_sizes[0] / 128;   // 50000
    const int E = in_sizes[1] / 64;    // 800000

    float* p = (float*)d_ws;
    float* h      = p; p += (size_t)N * 64;
    float* hi     = p; p += N;
    float* hj     = p; p += N;
    float* he     = p; p += N;
    float* ge     = p; p += E;
    float* acc_ea = p; p += (size_t)N * 64;
    int* deg_n = (int*)p; p += N;
    int* deg_e = (int*)p; p += N;
    int* off_n = (int*)p; p += N;
    int* off_e = (int*)p; p += N;
    int* cur_n = (int*)p; p += N;
    int* cur_e = (int*)p; p += N;
    int* adj_n = (int*)p; p += E;
    int* adj_e = (int*)p; p += (size_t)2 * E;

    k_init<<<256, 256, 0, stream>>>(deg_n, deg_e, N);
    k_gemm64<128, false><<<(N + 63) / 64, 256, 0, stream>>>(x, Wn, h, N, 64);
    k_scal<<<(N + 255) / 256, 256, 0, stream>>>(h, a_node, a_edge, hi, hj, he, N);
    k_ge<<<(E + 255) / 256, 256, 0, stream>>>(ea, We, a_edge, ge, E);
    k_count<<<1024, 256, 0, stream>>>(idx, deg_n, deg_e, E, N);
    k_scan<<<2, 1024, 0, stream>>>(deg_n, off_n, cur_n, deg_e, off_e, cur_e, N);
    k_fill<<<1024, 256, 0, stream>>>(idx, cur_n, cur_e, adj_n, adj_e, E, N);
    k_out_n<<<(N + 3) / 4, 256, 0, stream>>>(h, hi, hj, off_n, deg_n, adj_n, out, N);
    k_out_e<<<(N + 3) / 4, 256, 0, stream>>>(ea, he, ge, off_e, deg_e, adj_e, acc_ea, N);
    k_gemm64<64, true><<<(N + 63) / 64, 256, 0, stream>>>(acc_ea, We, out + 64, N, 128);
}